// Round 5
// baseline (3102.826 us; speedup 1.0000x reference)
//
#include <hip/hip_runtime.h>

typedef unsigned short u16;
typedef unsigned int u32;
typedef __attribute__((ext_vector_type(8))) short short8;
typedef __attribute__((ext_vector_type(4))) float f32x4;

#define T_TOK 2048
#define H_DIM 2048
#define NEXP 64
#define I_DIM 1408
#define SI_DIM 2816
#define BM 128
#define BK 32
#define MAXT 192

__device__ __forceinline__ u16 f2bf(float f) {
    u32 u = __builtin_bit_cast(u32, f);
    u32 r = u + 0x7FFFu + ((u >> 16) & 1u);
    return (u16)(r >> 16);
}

__device__ __forceinline__ short8 cvtB(f32x4 a, f32x4 b) {
    short8 o;
    o[0] = (short)f2bf(a[0]); o[1] = (short)f2bf(a[1]);
    o[2] = (short)f2bf(a[2]); o[3] = (short)f2bf(a[3]);
    o[4] = (short)f2bf(b[0]); o[5] = (short)f2bf(b[1]);
    o[6] = (short)f2bf(b[2]); o[7] = (short)f2bf(b[3]);
    return o;
}

__device__ __forceinline__ f32x4 mfma16(short8 a, short8 b, f32x4 c) {
    return __builtin_amdgcn_mfma_f32_16x16x32_bf16(a, b, c, 0, 0, 0);
}

#define SB0 __builtin_amdgcn_sched_barrier(0)
#define WAITVM(N) { asm volatile("s_waitcnt vmcnt(" #N ")" ::: "memory"); SB0; }

// ---------------- x -> bf16 ----------------
__global__ __launch_bounds__(256) void k_cvt(const float* __restrict__ x, u16* __restrict__ xb) {
    int i = (blockIdx.x * 256 + threadIdx.x) * 8;
    #pragma unroll
    for (int j = 0; j < 8; ++j) xb[i + j] = f2bf(x[i + j]);
}

// ---------------- gating logits: f64 accumulation ----------------
__global__ __launch_bounds__(256) void k_gate_logits(const float* __restrict__ x,
        const float* __restrict__ gw, float* __restrict__ logits) {
    __shared__ float xs[8][65];
    __shared__ float wsh[64][65];
    int tid = threadIdx.x;
    int t0 = blockIdx.x * 8;
    double acc0 = 0.0, acc1 = 0.0;
    int e = tid & 63, tg = tid >> 6; // tg in [0,4)
    for (int k0 = 0; k0 < H_DIM; k0 += 64) {
        #pragma unroll
        for (int s = 0; s < 2; ++s) {
            int idx = s * 256 + tid;
            int r = idx >> 6, k = idx & 63;
            xs[r][k] = x[(size_t)(t0 + r) * H_DIM + k0 + k];
        }
        #pragma unroll
        for (int s = 0; s < 16; ++s) {
            int idx = s * 256 + tid;
            int r = idx >> 6, k = idx & 63;
            wsh[r][k] = gw[(size_t)r * H_DIM + k0 + k];
        }
        __syncthreads();
        #pragma unroll 8
        for (int k = 0; k < 64; ++k) {
            double wv = (double)wsh[e][k];
            acc0 += (double)xs[tg][k] * wv;
            acc1 += (double)xs[tg + 4][k] * wv;
        }
        __syncthreads();
    }
    logits[(size_t)(t0 + tg) * NEXP + e] = (float)acc0;
    logits[(size_t)(t0 + tg + 4) * NEXP + e] = (float)acc1;
}

// ---------------- per-token group-restricted top-k ----------------
__global__ __launch_bounds__(256) void k_topk(const float* __restrict__ logits,
        const float* __restrict__ ebias, int* __restrict__ topk_idx,
        float* __restrict__ topk_w, int* __restrict__ counts) {
    __shared__ float bsh[64];
    if (threadIdx.x < 64) bsh[threadIdx.x] = ebias[threadIdx.x];
    __syncthreads();
    int t = blockIdx.x * 256 + threadIdx.x;
    float sc[64];
    #pragma unroll
    for (int e2 = 0; e2 < 64; ++e2) {
        float lg = logits[(size_t)t * 64 + e2];
        sc[e2] = 1.0f / (1.0f + expf(-lg));
    }
    float gsc[8];
    #pragma unroll
    for (int g = 0; g < 8; ++g) {
        float m1 = -1e30f, m2 = -1e30f;
        #pragma unroll
        for (int j = 0; j < 8; ++j) {
            float v = sc[g * 8 + j] + bsh[g * 8 + j];
            if (v > m1) { m2 = m1; m1 = v; }
            else if (v > m2) { m2 = v; }
        }
        gsc[g] = m1 + m2;
    }
    u32 gmask = 0;
    #pragma unroll
    for (int it = 0; it < 4; ++it) {
        float best = -1e30f; int bi = 0;
        #pragma unroll
        for (int g = 0; g < 8; ++g) {
            bool ok = !((gmask >> g) & 1u);
            if (ok && gsc[g] > best) { best = gsc[g]; bi = g; }
        }
        gmask |= 1u << bi;
    }
    unsigned long long avail = 0ull;
    #pragma unroll
    for (int g = 0; g < 8; ++g)
        if ((gmask >> g) & 1u) avail |= (0xFFull << (g * 8));
    float wsum = 0.f;
    int idx[8]; float wv[8];
    #pragma unroll
    for (int it = 0; it < 8; ++it) {
        float best = -1e30f, bw = 0.f; int bi = 0;
        #pragma unroll
        for (int e2 = 0; e2 < 64; ++e2) {
            bool ok = (avail >> e2) & 1ull;
            float v = sc[e2] + bsh[e2];
            if (ok && v > best) { best = v; bi = e2; bw = sc[e2]; }
        }
        avail &= ~(1ull << bi);
        idx[it] = bi; wv[it] = bw; wsum += bw;
    }
    float scale = 2.5f / (wsum + 1e-20f);
    #pragma unroll
    for (int it = 0; it < 8; ++it) {
        topk_idx[t * 8 + it] = idx[it];
        topk_w[t * 8 + it] = wv[it] * scale;
        atomicAdd(&counts[idx[it]], 1);
    }
}

// ---------------- prefix sum + tile list ----------------
__global__ void k_prefix(const int* __restrict__ counts, int* __restrict__ offsets,
                         int* __restrict__ tiles, int* __restrict__ ntiles) {
    if (threadIdx.x == 0) {
        int run = 0, nt = 0;
        for (int e = 0; e < 64; ++e) {
            offsets[e] = run;
            int c = counts[e];
            for (int m0 = 0; m0 < c; m0 += BM) tiles[nt++] = (e << 16) | m0;
            run += c;
        }
        offsets[64] = run;
        *ntiles = nt;
    }
}

// ---------------- scatter (t,k) -> per-expert lists ----------------
__global__ __launch_bounds__(256) void k_scatter(const int* __restrict__ topk_idx,
        const float* __restrict__ topk_w, const int* __restrict__ offsets,
        int* __restrict__ fill, int* __restrict__ tok_list, float* __restrict__ w_list) {
    int gid = blockIdx.x * 256 + threadIdx.x;
    int t = gid >> 3;
    int e = topk_idx[gid];
    int pos = offsets[e] + atomicAdd(&fill[e], 1);
    tok_list[pos] = t;
    w_list[pos] = topk_w[gid];
}

// ---------------- fused gate+up+silu*mul grouped GEMM ----------------
// Barrier-free: 4 waves/block, wave w owns n-cols [i0+w*16, +16), all BM=128 m-rows.
// A (bf16) and B (f32->bf16) load global->registers directly; depth-2 pipeline,
// counted vmcnt(12) = one step (8 A + 4 B dwordx4) in flight.
__global__ __launch_bounds__(256, 2) void k_gateup(
        const u16* __restrict__ xb,
        const float* __restrict__ gate_base, const float* __restrict__ up_base,
        const int* __restrict__ offsets, const int* __restrict__ tok_list,
        const int* __restrict__ tiles, const int* __restrict__ ntiles,
        u16* __restrict__ inter, int Irows) {
    int e, m0, seg, n;
    if (tiles) {
        if ((int)blockIdx.x >= *ntiles) return;
        int tt = tiles[blockIdx.x];
        e = tt >> 16; m0 = tt & 0xFFFF;
        seg = offsets[e]; n = offsets[e + 1] - seg;
    } else {
        e = 0; m0 = blockIdx.x * BM; seg = 0; n = T_TOK;
    }
    int i0 = blockIdx.y * 64;
    int w = threadIdx.x >> 6, lane = threadIdx.x & 63;

    const char* Bg = (const char*)(gate_base + (size_t)e * Irows * H_DIM);
    const char* Bu = (const char*)(up_base + (size_t)e * Irows * H_DIM);
    const char* Xb = (const char*)xb;

    u32 voffA[8];
    #pragma unroll
    for (int fm = 0; fm < 8; ++fm) {
        int p = m0 + fm * 16 + (lane & 15); if (p >= n) p = n - 1;
        int tok = tok_list ? tok_list[seg + p] : p;
        voffA[fm] = (u32)tok * (H_DIM * 2) + ((lane >> 4) * 16);
    }
    int brow = i0 + w * 16 + (lane & 15);
    u32 voffB = (u32)brow * (H_DIM * 4) + ((lane >> 4) * 32);

    f32x4 accg[8], accu[8];
    #pragma unroll
    for (int fm = 0; fm < 8; ++fm) {
        accg[fm][0]=0.f; accg[fm][1]=0.f; accg[fm][2]=0.f; accg[fm][3]=0.f;
        accu[fm][0]=0.f; accu[fm][1]=0.f; accu[fm][2]=0.f; accu[fm][3]=0.f;
    }

    short8 aX[8], aY[8];
    f32x4 gX0, gX1, uX0, uX1, gY0, gY1, uY0, uY1;

    auto issue = [&](int t, short8* A, f32x4& g0, f32x4& g1, f32x4& u0, f32x4& u1) {
        const char* xk = Xb + t * (BK * 2);
        #pragma unroll
        for (int fm = 0; fm < 8; ++fm) A[fm] = *(const short8*)(xk + voffA[fm]);
        const char* gk = Bg + t * (BK * 4);
        const char* uk = Bu + t * (BK * 4);
        g0 = *(const f32x4*)(gk + voffB); g1 = *(const f32x4*)(gk + voffB + 16);
        u0 = *(const f32x4*)(uk + voffB); u1 = *(const f32x4*)(uk + voffB + 16);
    };
    auto consume = [&](short8* A, f32x4 g0, f32x4 g1, f32x4 u0, f32x4 u1) {
        short8 bg = cvtB(g0, g1), bu = cvtB(u0, u1);
        #pragma unroll
        for (int fm = 0; fm < 8; ++fm) {
            accg[fm] = mfma16(A[fm], bg, accg[fm]);
            accu[fm] = mfma16(A[fm], bu, accu[fm]);
        }
    };

    const int NK = H_DIM / BK; // 64, even
    issue(0, aX, gX0, gX1, uX0, uX1); SB0;
    issue(1, aY, gY0, gY1, uY0, uY1); SB0;

    for (int t = 0; t < NK; t += 2) {
        WAITVM(12);
        consume(aX, gX0, gX1, uX0, uX1); SB0;
        if (t + 2 < NK) { issue(t + 2, aX, gX0, gX1, uX0, uX1); } SB0;
        if (t + 2 < NK) { WAITVM(12); } else { WAITVM(0); }
        consume(aY, gY0, gY1, uY0, uY1); SB0;
        if (t + 3 < NK) { issue(t + 3, aY, gY0, gY1, uY0, uY1); } SB0;
    }

    int col = i0 + w * 16 + (lane & 15);
    int rbase = m0 + (lane >> 4) * 4;
    #pragma unroll
    for (int fm = 0; fm < 8; ++fm) {
        #pragma unroll
        for (int r = 0; r < 4; ++r) {
            int p = rbase + fm * 16 + r;
            if (p < n) {
                float g = accg[fm][r], u = accu[fm][r];
                float val = g / (1.0f + expf(-g)) * u;
                inter[(size_t)(seg + p) * Irows + col] = f2bf(val);
            }
        }
    }
}

// ---------------- down-proj grouped GEMM, weighted atomic scatter ----------------
// Same barrier-free structure; A = inter rows (contiguous in segment), 10 loads/step.
__global__ __launch_bounds__(256, 2) void k_down(
        const u16* __restrict__ inter, int Kdim,
        const float* __restrict__ down_base,
        const int* __restrict__ offsets, const int* __restrict__ tok_list,
        const int* __restrict__ tiles, const int* __restrict__ ntiles,
        const float* __restrict__ w_list,
        float* __restrict__ out) {
    int e, m0, seg, n;
    if (tiles) {
        if ((int)blockIdx.x >= *ntiles) return;
        int tt = tiles[blockIdx.x];
        e = tt >> 16; m0 = tt & 0xFFFF;
        seg = offsets[e]; n = offsets[e + 1] - seg;
    } else {
        e = 0; m0 = blockIdx.x * BM; seg = 0; n = T_TOK;
    }
    int h0 = blockIdx.y * 64;
    int w = threadIdx.x >> 6, lane = threadIdx.x & 63;

    const char* Bd = (const char*)(down_base + (size_t)e * H_DIM * Kdim);
    const char* Ai = (const char*)inter;

    u32 voffA[8];
    #pragma unroll
    for (int fm = 0; fm < 8; ++fm) {
        int p = m0 + fm * 16 + (lane & 15); if (p >= n) p = n - 1;
        voffA[fm] = (u32)(seg + p) * (Kdim * 2) + ((lane >> 4) * 16);
    }
    int brow = h0 + w * 16 + (lane & 15);
    u32 voffB = (u32)brow * (Kdim * 4) + ((lane >> 4) * 32);

    f32x4 acc[8];
    #pragma unroll
    for (int fm = 0; fm < 8; ++fm) { acc[fm][0]=0.f; acc[fm][1]=0.f; acc[fm][2]=0.f; acc[fm][3]=0.f; }

    short8 aX[8], aY[8];
    f32x4 dX0, dX1, dY0, dY1;

    auto issue = [&](int t, short8* A, f32x4& d0, f32x4& d1) {
        const char* ak = Ai + t * (BK * 2);
        #pragma unroll
        for (int fm = 0; fm < 8; ++fm) A[fm] = *(const short8*)(ak + voffA[fm]);
        const char* dk = Bd + t * (BK * 4);
        d0 = *(const f32x4*)(dk + voffB); d1 = *(const f32x4*)(dk + voffB + 16);
    };
    auto consume = [&](short8* A, f32x4 d0, f32x4 d1) {
        short8 b = cvtB(d0, d1);
        #pragma unroll
        for (int fm = 0; fm < 8; ++fm) acc[fm] = mfma16(A[fm], b, acc[fm]);
    };

    const int NK = Kdim / BK; // 44 or 88, even
    issue(0, aX, dX0, dX1); SB0;
    issue(1, aY, dY0, dY1); SB0;

    for (int t = 0; t < NK; t += 2) {
        WAITVM(10);
        consume(aX, dX0, dX1); SB0;
        if (t + 2 < NK) { issue(t + 2, aX, dX0, dX1); } SB0;
        if (t + 2 < NK) { WAITVM(10); } else { WAITVM(0); }
        consume(aY, dY0, dY1); SB0;
        if (t + 3 < NK) { issue(t + 3, aY, dY0, dY1); } SB0;
    }

    int col = h0 + w * 16 + (lane & 15);
    int rbase = m0 + (lane >> 4) * 4;
    #pragma unroll
    for (int fm = 0; fm < 8; ++fm) {
        #pragma unroll
        for (int r = 0; r < 4; ++r) {
            int p = rbase + fm * 16 + r;
            if (p < n) {
                int tok = tok_list ? tok_list[seg + p] : p;
                float wt = w_list ? w_list[seg + p] : 1.0f;
                atomicAdd(&out[(size_t)tok * H_DIM + col], acc[fm][r] * wt);
            }
        }
    }
}

extern "C" void kernel_launch(void* const* d_in, const int* in_sizes, int n_in,
                              void* d_out, int out_size, void* d_ws, size_t ws_size,
                              hipStream_t stream) {
    const float* x         = (const float*)d_in[0];
    const float* gate_w    = (const float*)d_in[1];
    const float* e_bias    = (const float*)d_in[2];
    const float* gate_proj = (const float*)d_in[3];
    const float* up_proj   = (const float*)d_in[4];
    const float* down_proj = (const float*)d_in[5];
    const float* sgw       = (const float*)d_in[6];
    const float* suw       = (const float*)d_in[7];
    const float* sdw       = (const float*)d_in[8];
    float* out = (float*)d_out;

    char* ws = (char*)d_ws;
    size_t off = 0;
    auto alloc = [&](size_t bytes) -> char* {
        char* p = ws + off;
        off += (bytes + 255) & ~(size_t)255;
        return p;
    };
    float* logits   = (float*)alloc((size_t)T_TOK * 64 * 4);
    int*   topk_idx = (int*)  alloc((size_t)T_TOK * 8 * 4);
    float* topk_w   = (float*)alloc((size_t)T_TOK * 8 * 4);
    int*   counts   = (int*)  alloc(256);   // [64]
    int*   offsets  = (int*)  alloc(512);   // [65]
    int*   fill     = (int*)  alloc(256);   // [64]
    int*   tiles    = (int*)  alloc(MAXT * 4);
    int*   ntiles   = (int*)  alloc(256);
    int*   tok_list = (int*)  alloc((size_t)T_TOK * 8 * 4);
    float* w_list   = (float*)alloc((size_t)T_TOK * 8 * 4);
    u16*   xb       = (u16*)  alloc((size_t)T_TOK * H_DIM * 2);
    u16*   inter    = (u16*)  alloc((size_t)T_TOK * 8 * I_DIM * 2); // reused for shared

    hipMemsetAsync(d_out, 0, (size_t)out_size * 4, stream);
    hipMemsetAsync(counts, 0, 1024, stream); // counts + offsets + fill

    k_cvt<<<(T_TOK * H_DIM) / 2048, 256, 0, stream>>>(x, xb);
    k_gate_logits<<<T_TOK / 8, 256, 0, stream>>>(x, gate_w, logits);
    k_topk<<<T_TOK / 256, 256, 0, stream>>>(logits, e_bias, topk_idx, topk_w, counts);
    k_prefix<<<1, 64, 0, stream>>>(counts, offsets, tiles, ntiles);
    k_scatter<<<(T_TOK * 8) / 256, 256, 0, stream>>>(topk_idx, topk_w, offsets, fill, tok_list, w_list);

    // routed experts
    k_gateup<<<dim3(MAXT, I_DIM / 64), 256, 0, stream>>>(
        xb, gate_proj, up_proj, offsets, tok_list, tiles, ntiles, inter, I_DIM);
    k_down<<<dim3(MAXT, H_DIM / 64), 256, 0, stream>>>(
        inter, I_DIM, down_proj, offsets, tok_list, tiles, ntiles, w_list, out);

    // shared experts
    k_gateup<<<dim3(T_TOK / BM, SI_DIM / 64), 256, 0, stream>>>(
        xb, sgw, suw, nullptr, nullptr, nullptr, nullptr, inter, SI_DIM);
    k_down<<<dim3(T_TOK / BM, H_DIM / 64), 256, 0, stream>>>(
        inter, SI_DIM, sdw, nullptr, nullptr, nullptr, nullptr, nullptr, out);
}

// Round 8
// 1484.055 us; speedup vs baseline: 2.0908x; 2.0908x over previous
//
#include <hip/hip_runtime.h>

typedef unsigned short u16;
typedef unsigned int u32;
typedef __attribute__((ext_vector_type(8))) short short8;
typedef __attribute__((ext_vector_type(8))) u16 ushort8;
typedef __attribute__((ext_vector_type(4))) float f32x4;

#define T_TOK 2048
#define H_DIM 2048
#define NEXP 64
#define I_DIM 1408
#define SI_DIM 2816
#define BM 128
#define BK 64
#define MAXT 256

__device__ __forceinline__ u16 f2bf(float f) {
    u32 u = __builtin_bit_cast(u32, f);
    u32 r = u + 0x7FFFu + ((u >> 16) & 1u);
    return (u16)(r >> 16);
}

__device__ __forceinline__ ushort8 cvt8(f32x4 a, f32x4 b) {
    ushort8 o;
    o[0] = f2bf(a[0]); o[1] = f2bf(a[1]); o[2] = f2bf(a[2]); o[3] = f2bf(a[3]);
    o[4] = f2bf(b[0]); o[5] = f2bf(b[1]); o[6] = f2bf(b[2]); o[7] = f2bf(b[3]);
    return o;
}

__device__ __forceinline__ f32x4 mfma16(short8 a, short8 b, f32x4 c) {
    return __builtin_amdgcn_mfma_f32_16x16x32_bf16(a, b, c, 0, 0, 0);
}

// ---------------- x -> bf16 ----------------
__global__ __launch_bounds__(256) void k_cvt(const float* __restrict__ x, u16* __restrict__ xb) {
    int i = (blockIdx.x * 256 + threadIdx.x) * 8;
    f32x4 v0 = *(const f32x4*)(x + i);
    f32x4 v1 = *(const f32x4*)(x + i + 4);
    *(ushort8*)(xb + i) = cvt8(v0, v1);
}

// ---------------- gating logits: f64 accumulation ----------------
__global__ __launch_bounds__(256) void k_gate_logits(const float* __restrict__ x,
        const float* __restrict__ gw, float* __restrict__ logits) {
    __shared__ float xs[8][65];
    __shared__ float wsh[64][65];
    int tid = threadIdx.x;
    int t0 = blockIdx.x * 8;
    double acc0 = 0.0, acc1 = 0.0;
    int e = tid & 63, tg = tid >> 6; // tg in [0,4)
    for (int k0 = 0; k0 < H_DIM; k0 += 64) {
        #pragma unroll
        for (int s = 0; s < 2; ++s) {
            int idx = s * 256 + tid;
            int r = idx >> 6, k = idx & 63;
            xs[r][k] = x[(size_t)(t0 + r) * H_DIM + k0 + k];
        }
        #pragma unroll
        for (int s = 0; s < 16; ++s) {
            int idx = s * 256 + tid;
            int r = idx >> 6, k = idx & 63;
            wsh[r][k] = gw[(size_t)r * H_DIM + k0 + k];
        }
        __syncthreads();
        #pragma unroll 8
        for (int k = 0; k < 64; ++k) {
            double wv = (double)wsh[e][k];
            acc0 += (double)xs[tg][k] * wv;
            acc1 += (double)xs[tg + 4][k] * wv;
        }
        __syncthreads();
    }
    logits[(size_t)(t0 + tg) * NEXP + e] = (float)acc0;
    logits[(size_t)(t0 + tg + 4) * NEXP + e] = (float)acc1;
}

// ---------------- per-token group-restricted top-k ----------------
__global__ __launch_bounds__(256) void k_topk(const float* __restrict__ logits,
        const float* __restrict__ ebias, int* __restrict__ topk_idx,
        float* __restrict__ topk_w, int* __restrict__ counts) {
    __shared__ float bsh[64];
    if (threadIdx.x < 64) bsh[threadIdx.x] = ebias[threadIdx.x];
    __syncthreads();
    int t = blockIdx.x * 256 + threadIdx.x;
    float sc[64];
    #pragma unroll
    for (int e2 = 0; e2 < 64; ++e2) {
        float lg = logits[(size_t)t * 64 + e2];
        sc[e2] = 1.0f / (1.0f + expf(-lg));
    }
    float gsc[8];
    #pragma unroll
    for (int g = 0; g < 8; ++g) {
        float m1 = -1e30f, m2 = -1e30f;
        #pragma unroll
        for (int j = 0; j < 8; ++j) {
            float v = sc[g * 8 + j] + bsh[g * 8 + j];
            if (v > m1) { m2 = m1; m1 = v; }
            else if (v > m2) { m2 = v; }
        }
        gsc[g] = m1 + m2;
    }
    u32 gmask = 0;
    #pragma unroll
    for (int it = 0; it < 4; ++it) {
        float best = -1e30f; int bi = 0;
        #pragma unroll
        for (int g = 0; g < 8; ++g) {
            bool ok = !((gmask >> g) & 1u);
            if (ok && gsc[g] > best) { best = gsc[g]; bi = g; }
        }
        gmask |= 1u << bi;
    }
    unsigned long long avail = 0ull;
    #pragma unroll
    for (int g = 0; g < 8; ++g)
        if ((gmask >> g) & 1u) avail |= (0xFFull << (g * 8));
    float wsum = 0.f;
    int idx[8]; float wv[8];
    #pragma unroll
    for (int it = 0; it < 8; ++it) {
        float best = -1e30f, bw = 0.f; int bi = 0;
        #pragma unroll
        for (int e2 = 0; e2 < 64; ++e2) {
            bool ok = (avail >> e2) & 1ull;
            float v = sc[e2] + bsh[e2];
            if (ok && v > best) { best = v; bi = e2; bw = sc[e2]; }
        }
        avail &= ~(1ull << bi);
        idx[it] = bi; wv[it] = bw; wsum += bw;
    }
    float scale = 2.5f / (wsum + 1e-20f);
    #pragma unroll
    for (int it = 0; it < 8; ++it) {
        topk_idx[t * 8 + it] = idx[it];
        topk_w[t * 8 + it] = wv[it] * scale;
        atomicAdd(&counts[idx[it]], 1);
    }
}

// ---------------- prefix sum + tile list (BM=128) ----------------
__global__ void k_prefix(const int* __restrict__ counts, int* __restrict__ offsets,
                         int* __restrict__ tiles, int* __restrict__ ntiles) {
    if (threadIdx.x == 0) {
        int run = 0, nt = 0;
        for (int e = 0; e < 64; ++e) {
            offsets[e] = run;
            int c = counts[e];
            for (int m0 = 0; m0 < c && nt < MAXT; m0 += BM) tiles[nt++] = (e << 16) | m0;
            run += c;
        }
        offsets[64] = run;
        *ntiles = nt;
    }
}

// ---------------- scatter (t,k) -> per-expert lists ----------------
__global__ __launch_bounds__(256) void k_scatter(const int* __restrict__ topk_idx,
        const float* __restrict__ topk_w, const int* __restrict__ offsets,
        int* __restrict__ fill, int* __restrict__ tok_list, float* __restrict__ w_list) {
    int gid = blockIdx.x * 256 + threadIdx.x;
    int t = gid >> 3;
    int e = topk_idx[gid];
    int pos = offsets[e] + atomicAdd(&fill[e], 1);
    tok_list[pos] = t;
    w_list[pos] = topk_w[gid];
}

// ---------------- fused gate+up+silu*mul grouped GEMM ----------------
// 128m x 64n(gate+up), BK=64, 4 waves (each 32m x 64n x {g,u}).
// Double-buffered LDS, ONE barrier per K-step, compiler-scheduled prefetch.
__global__ __launch_bounds__(256, 2) void k_gateup(
        const u16* __restrict__ xb,
        const float* __restrict__ gate_base, const float* __restrict__ up_base,
        const int* __restrict__ offsets, const int* __restrict__ tok_list,
        const int* __restrict__ tiles, const int* __restrict__ ntiles,
        u16* __restrict__ inter, int Irows) {
    int e, m0, seg, n;
    if (tiles) {
        if ((int)blockIdx.x >= *ntiles) return;
        int tt = tiles[blockIdx.x];
        e = tt >> 16; m0 = tt & 0xFFFF;
        seg = offsets[e]; n = offsets[e + 1] - seg;
    } else {
        e = 0; m0 = blockIdx.x * BM; seg = 0; n = T_TOK;
    }
    if (n <= 0 || m0 >= n) return;
    int i0 = blockIdx.y * 64;

    const float* Bg = gate_base + (size_t)e * Irows * H_DIM;
    const float* Bu = up_base + (size_t)e * Irows * H_DIM;

    __shared__ u16 As[2][BM * BK];    // 2 x 16KB
    __shared__ u16 Bsg[2][64 * BK];   // 2 x 8KB
    __shared__ u16 Bsu[2][64 * BK];   // 2 x 8KB

    int tid = threadIdx.x;
    int w = tid >> 6, lane = tid & 63;

    // A: 1024 slots (r 0..127, cb 0..7), 4 slots/thread
    const u16* asrc[4]; int adst[4];
    #pragma unroll
    for (int s = 0; s < 4; ++s) {
        int slot = s * 256 + tid;
        int r = slot >> 3, cb = slot & 7;
        int p = m0 + r; if (p >= n) p = n - 1;
        int tok = tok_list ? tok_list[seg + p] : p;
        asrc[s] = xb + (size_t)tok * H_DIM + cb * 8;
        adst[s] = r * BK + ((cb ^ (r & 7)) * 8);
    }
    // B: 512 slots per matrix (r 0..63, cb 0..7), 2 slots/thread/matrix
    const float* bgsrc[2]; const float* busrc[2]; int bdst[2];
    #pragma unroll
    for (int s = 0; s < 2; ++s) {
        int slot = s * 256 + tid;
        int r = slot >> 3, cb = slot & 7;
        bgsrc[s] = Bg + (size_t)(i0 + r) * H_DIM + cb * 8;
        busrc[s] = Bu + (size_t)(i0 + r) * H_DIM + cb * 8;
        bdst[s] = r * BK + ((cb ^ (r & 7)) * 8);
    }

    f32x4 zero; zero[0] = 0.f; zero[1] = 0.f; zero[2] = 0.f; zero[3] = 0.f;
    f32x4 accg[2][4], accu[2][4];
    #pragma unroll
    for (int a = 0; a < 2; ++a)
        #pragma unroll
        for (int b = 0; b < 4; ++b) { accg[a][b] = zero; accu[a][b] = zero; }

    // staged regs (statically indexed)
    short8 stA[4];
    f32x4 stG[2][2], stU[2][2];

    auto ldregs = [&](int k0) {
        #pragma unroll
        for (int s = 0; s < 4; ++s) stA[s] = *(const short8*)(asrc[s] + k0);
        #pragma unroll
        for (int s = 0; s < 2; ++s) {
            stG[s][0] = *(const f32x4*)(bgsrc[s] + k0);
            stG[s][1] = *(const f32x4*)(bgsrc[s] + k0 + 4);
            stU[s][0] = *(const f32x4*)(busrc[s] + k0);
            stU[s][1] = *(const f32x4*)(busrc[s] + k0 + 4);
        }
    };
    auto dswrite = [&](int buf) {
        #pragma unroll
        for (int s = 0; s < 4; ++s) *(ushort8*)(&As[buf][adst[s]]) = *(const ushort8*)&stA[s];
        #pragma unroll
        for (int s = 0; s < 2; ++s) {
            *(ushort8*)(&Bsg[buf][bdst[s]]) = cvt8(stG[s][0], stG[s][1]);
            *(ushort8*)(&Bsu[buf][bdst[s]]) = cvt8(stU[s][0], stU[s][1]);
        }
    };
    auto mmaStep = [&](int buf) {
        #pragma unroll
        for (int ks = 0; ks < 2; ++ks) {
            short8 a[2];
            #pragma unroll
            for (int fm = 0; fm < 2; ++fm) {
                int row = w * 32 + fm * 16 + (lane & 15);
                int cb = ks * 4 + (lane >> 4);
                a[fm] = *(const short8*)(&As[buf][row * BK + ((cb ^ (row & 7)) * 8)]);
            }
            #pragma unroll
            for (int fn = 0; fn < 4; ++fn) {
                int brow = fn * 16 + (lane & 15);
                int cb = ks * 4 + (lane >> 4);
                int boff = brow * BK + ((cb ^ (brow & 7)) * 8);
                short8 bg = *(const short8*)(&Bsg[buf][boff]);
                short8 bu = *(const short8*)(&Bsu[buf][boff]);
                accg[0][fn] = mfma16(a[0], bg, accg[0][fn]);
                accg[1][fn] = mfma16(a[1], bg, accg[1][fn]);
                accu[0][fn] = mfma16(a[0], bu, accu[0][fn]);
                accu[1][fn] = mfma16(a[1], bu, accu[1][fn]);
            }
        }
    };

    const int NK = H_DIM / BK; // 32
    ldregs(0);
    dswrite(0);
    __syncthreads();
    for (int t = 0; t < NK; ++t) {
        if (t + 1 < NK) ldregs((t + 1) * BK);
        mmaStep(t & 1);
        if (t + 1 < NK) dswrite((t + 1) & 1);
        __syncthreads();
    }

    int r0 = (lane >> 4) * 4, cc = lane & 15;
    #pragma unroll
    for (int fm = 0; fm < 2; ++fm) {
        #pragma unroll
        for (int r = 0; r < 4; ++r) {
            int p = m0 + w * 32 + fm * 16 + r0 + r;
            if (p < n) {
                size_t rowb = (size_t)(seg + p) * Irows + i0;
                #pragma unroll
                for (int fn = 0; fn < 4; ++fn) {
                    float g = accg[fm][fn][r], u = accu[fm][fn][r];
                    float val = g / (1.0f + expf(-g)) * u;
                    inter[rowb + fn * 16 + cc] = f2bf(val);
                }
            }
        }
    }
}

// ---------------- down-proj grouped GEMM ----------------
// 128m x 128n, BK=64, 4 waves (each 32m x 128n). Same dbuf single-barrier scheme.
// w_list==nullptr => plain store (shared experts, run FIRST); else atomicAdd*wt.
__global__ __launch_bounds__(256, 2) void k_down(
        const u16* __restrict__ inter, int Kdim,
        const float* __restrict__ down_base,
        const int* __restrict__ offsets, const int* __restrict__ tok_list,
        const int* __restrict__ tiles, const int* __restrict__ ntiles,
        const float* __restrict__ w_list,
        float* __restrict__ out) {
    int e, m0, seg, n;
    if (tiles) {
        if ((int)blockIdx.x >= *ntiles) return;
        int tt = tiles[blockIdx.x];
        e = tt >> 16; m0 = tt & 0xFFFF;
        seg = offsets[e]; n = offsets[e + 1] - seg;
    } else {
        e = 0; m0 = blockIdx.x * BM; seg = 0; n = T_TOK;
    }
    if (n <= 0 || m0 >= n) return;
    int h0 = blockIdx.y * 128;

    const float* Bd = down_base + (size_t)e * H_DIM * Kdim;

    __shared__ u16 As[2][BM * BK];    // 2 x 16KB
    __shared__ u16 Bs[2][128 * BK];   // 2 x 16KB

    int tid = threadIdx.x;
    int w = tid >> 6, lane = tid & 63;

    const u16* asrc[4]; int adst[4];
    #pragma unroll
    for (int s = 0; s < 4; ++s) {
        int slot = s * 256 + tid;
        int r = slot >> 3, cb = slot & 7;
        int p = m0 + r; if (p >= n) p = n - 1;
        asrc[s] = inter + (size_t)(seg + p) * Kdim + cb * 8;
        adst[s] = r * BK + ((cb ^ (r & 7)) * 8);
    }
    const float* bsrc[4]; int bdst[4];
    #pragma unroll
    for (int s = 0; s < 4; ++s) {
        int slot = s * 256 + tid;
        int r = slot >> 3, cb = slot & 7;
        bsrc[s] = Bd + (size_t)(h0 + r) * Kdim + cb * 8;
        bdst[s] = r * BK + ((cb ^ (r & 7)) * 8);
    }

    f32x4 zero; zero[0] = 0.f; zero[1] = 0.f; zero[2] = 0.f; zero[3] = 0.f;
    f32x4 acc[2][8];
    #pragma unroll
    for (int a = 0; a < 2; ++a)
        #pragma unroll
        for (int b = 0; b < 8; ++b) acc[a][b] = zero;

    short8 stA[4];
    f32x4 stB[4][2];

    auto ldregs = [&](int k0) {
        #pragma unroll
        for (int s = 0; s < 4; ++s) stA[s] = *(const short8*)(asrc[s] + k0);
        #pragma unroll
        for (int s = 0; s < 4; ++s) {
            stB[s][0] = *(const f32x4*)(bsrc[s] + k0);
            stB[s][1] = *(const f32x4*)(bsrc[s] + k0 + 4);
        }
    };
    auto dswrite = [&](int buf) {
        #pragma unroll
        for (int s = 0; s < 4; ++s) *(ushort8*)(&As[buf][adst[s]]) = *(const ushort8*)&stA[s];
        #pragma unroll
        for (int s = 0; s < 4; ++s)
            *(ushort8*)(&Bs[buf][bdst[s]]) = cvt8(stB[s][0], stB[s][1]);
    };
    auto mmaStep = [&](int buf) {
        #pragma unroll
        for (int ks = 0; ks < 2; ++ks) {
            short8 a[2];
            #pragma unroll
            for (int fm = 0; fm < 2; ++fm) {
                int row = w * 32 + fm * 16 + (lane & 15);
                int cb = ks * 4 + (lane >> 4);
                a[fm] = *(const short8*)(&As[buf][row * BK + ((cb ^ (row & 7)) * 8)]);
            }
            #pragma unroll
            for (int fn = 0; fn < 8; ++fn) {
                int brow = fn * 16 + (lane & 15);
                int cb = ks * 4 + (lane >> 4);
                short8 b = *(const short8*)(&Bs[buf][brow * BK + ((cb ^ (brow & 7)) * 8)]);
                acc[0][fn] = mfma16(a[0], b, acc[0][fn]);
                acc[1][fn] = mfma16(a[1], b, acc[1][fn]);
            }
        }
    };

    const int NK = Kdim / BK; // 22 or 44
    ldregs(0);
    dswrite(0);
    __syncthreads();
    for (int t = 0; t < NK; ++t) {
        if (t + 1 < NK) ldregs((t + 1) * BK);
        mmaStep(t & 1);
        if (t + 1 < NK) dswrite((t + 1) & 1);
        __syncthreads();
    }

    int r0 = (lane >> 4) * 4, cc = lane & 15;
    #pragma unroll
    for (int fm = 0; fm < 2; ++fm) {
        #pragma unroll
        for (int r = 0; r < 4; ++r) {
            int p = m0 + w * 32 + fm * 16 + r0 + r;
            if (p < n) {
                int tok = tok_list ? tok_list[seg + p] : p;
                size_t ob = (size_t)tok * H_DIM + h0 + cc;
                if (w_list) {
                    float wt = w_list[seg + p];
                    #pragma unroll
                    for (int fn = 0; fn < 8; ++fn)
                        atomicAdd(&out[ob + fn * 16], acc[fm][fn][r] * wt);
                } else {
                    #pragma unroll
                    for (int fn = 0; fn < 8; ++fn)
                        out[ob + fn * 16] = acc[fm][fn][r];
                }
            }
        }
    }
}

extern "C" void kernel_launch(void* const* d_in, const int* in_sizes, int n_in,
                              void* d_out, int out_size, void* d_ws, size_t ws_size,
                              hipStream_t stream) {
    const float* x         = (const float*)d_in[0];
    const float* gate_w    = (const float*)d_in[1];
    const float* e_bias    = (const float*)d_in[2];
    const float* gate_proj = (const float*)d_in[3];
    const float* up_proj   = (const float*)d_in[4];
    const float* down_proj = (const float*)d_in[5];
    const float* sgw       = (const float*)d_in[6];
    const float* suw       = (const float*)d_in[7];
    const float* sdw       = (const float*)d_in[8];
    float* out = (float*)d_out;

    char* ws = (char*)d_ws;
    size_t off = 0;
    auto alloc = [&](size_t bytes) -> char* {
        char* p = ws + off;
        off += (bytes + 255) & ~(size_t)255;
        return p;
    };
    float* logits   = (float*)alloc((size_t)T_TOK * 64 * 4);
    int*   topk_idx = (int*)  alloc((size_t)T_TOK * 8 * 4);
    float* topk_w   = (float*)alloc((size_t)T_TOK * 8 * 4);
    int*   counts   = (int*)  alloc(256);   // [64]
    int*   offsets  = (int*)  alloc(512);   // [65]
    int*   fill     = (int*)  alloc(256);   // [64]
    int*   tiles    = (int*)  alloc(MAXT * 4);
    int*   ntiles   = (int*)  alloc(256);
    int*   tok_list = (int*)  alloc((size_t)T_TOK * 8 * 4);
    float* w_list   = (float*)alloc((size_t)T_TOK * 8 * 4);
    u16*   xb       = (u16*)  alloc((size_t)T_TOK * H_DIM * 2);
    u16*   inter    = (u16*)  alloc((size_t)T_TOK * 8 * I_DIM * 2); // reused for shared

    hipMemsetAsync(counts, 0, 1024, stream); // counts + offsets + fill

    k_cvt<<<(T_TOK * H_DIM) / 2048, 256, 0, stream>>>(x, xb);
    k_gate_logits<<<T_TOK / 8, 256, 0, stream>>>(x, gate_w, logits);
    k_topk<<<T_TOK / 256, 256, 0, stream>>>(logits, e_bias, topk_idx, topk_w, counts);
    k_prefix<<<1, 64, 0, stream>>>(counts, offsets, tiles, ntiles);
    k_scatter<<<(T_TOK * 8) / 256, 256, 0, stream>>>(topk_idx, topk_w, offsets, fill, tok_list, w_list);

    // shared experts FIRST: shared k_down does plain stores covering all of out
    k_gateup<<<dim3(T_TOK / BM, SI_DIM / 64), 256, 0, stream>>>(
        xb, sgw, suw, nullptr, nullptr, nullptr, nullptr, inter, SI_DIM);
    k_down<<<dim3(T_TOK / BM, H_DIM / 128), 256, 0, stream>>>(
        inter, SI_DIM, sdw, nullptr, nullptr, nullptr, nullptr, nullptr, out);

    // routed experts accumulate on top via atomics
    k_gateup<<<dim3(MAXT, I_DIM / 64), 256, 0, stream>>>(
        xb, gate_proj, up_proj, offsets, tok_list, tiles, ntiles, inter, I_DIM);
    k_down<<<dim3(MAXT, H_DIM / 128), 256, 0, stream>>>(
        inter, I_DIM, down_proj, offsets, tok_list, tiles, ntiles, w_list, out);
}